// Round 9
// baseline (220.448 us; speedup 1.0000x reference)
//
#include <hip/hip_runtime.h>
#include <stdint.h>

#define AS1q __attribute__((address_space(1)))
#define AS3q __attribute__((address_space(3)))

typedef unsigned short US;
typedef __bf16 bf16x8 __attribute__((ext_vector_type(8)));
typedef float f32x4 __attribute__((ext_vector_type(4)));
typedef float f32x16 __attribute__((ext_vector_type(16)));
typedef float f32x2 __attribute__((ext_vector_type(2)));
typedef __bf16 bf16x2 __attribute__((ext_vector_type(2)));

#define LOG2E 1.44269504088896340736f

__device__ __forceinline__ US f2bf(float f) {
  union { float f; uint32_t u; } c; c.f = f;
  uint32_t u = c.u;
  return (US)((u + 0x7fffu + ((u >> 16) & 1u)) >> 16);
}

__device__ __forceinline__ bf16x8 asb(uint4 u) {
  union { uint4 u; bf16x8 b; } c; c.u = u; return c.b;
}

__device__ __forceinline__ uint32_t pk2(float a, float b) {
  f32x2 fv; fv[0] = a; fv[1] = b;
  bf16x2 bb = __builtin_convertvector(fv, bf16x2);
  union { bf16x2 b; uint32_t u; } c; c.b = bb; return c.u;
}

__device__ __forceinline__ void gload16(const void* g, void* l) {
  __builtin_amdgcn_global_load_lds((AS1q void*)(void*)g, (AS3q void*)l, 16, 0, 0);
}

// ------------- prep: 4 weight transposes only (q/k/v cast fused into gemm_qkv) ------
__global__ void prep_kernel(const float* __restrict__ w0, const float* __restrict__ w1,
                            const float* __restrict__ w2, const float* __restrict__ w3,
                            US* __restrict__ t0, US* __restrict__ t1,
                            US* __restrict__ t2, US* __restrict__ t3) {
  __shared__ US T[64 * 68];
  const int idx = blockIdx.x;
  const int t = threadIdx.x;
  const int wsel = idx >> 8, rem = idx & 255;
  const int n0 = (rem & 15) * 64, k0 = (rem >> 4) * 64;
  const float* W; US* Wt;
  if (wsel == 0)      { W = w0; Wt = t0; }
  else if (wsel == 1) { W = w1; Wt = t1; }
  else if (wsel == 2) { W = w2; Wt = t2; }
  else                { W = w3; Wt = t3; }
#pragma unroll
  for (int it = 0; it < 4; ++it) {
    int p = t + it * 256;
    int row = p >> 4, c4 = (p & 15) * 4;
    float4 f = *(const float4*)&W[(k0 + row) * 1024 + n0 + c4];
    ushort4 u;
    u.x = f2bf(f.x); u.y = f2bf(f.y); u.z = f2bf(f.z); u.w = f2bf(f.w);
    *(ushort4*)&T[row * 68 + c4] = u;
  }
  __syncthreads();
#pragma unroll
  for (int it = 0; it < 4; ++it) {
    int p = t + it * 256;
    int rn = p >> 4, ck = (p & 15) * 4;
    ushort4 o;
    o.x = T[(ck + 0) * 68 + rn];
    o.y = T[(ck + 1) * 68 + rn];
    o.z = T[(ck + 2) * 68 + rn];
    o.w = T[(ck + 3) * 68 + rn];
    *(ushort4*)&Wt[(n0 + rn) * 1024 + k0 + ck] = o;
  }
}

// ------------- QKV GEMM core: 128x128, BK=64, fused fp32->bf16 A, PIPELINED ---------
// A (fp32) is reg-staged one iteration AHEAD: per iter, cvt+ds_write uses regs loaded
// last iter; next iter's 8 loads are issued before a COUNTED barrier so they stay in
// flight across it. Raw s_barrier + s_waitcnt vmcnt(8) (B's 4 global_load_lds are the
// 4 oldest of 12 outstanding -> retired; the 8 A-loads survive). Compiler memory
// fences pin per-wave vmem issue order [A_prev][B x4][A_next x8] so the count is
// provable. Last iteration peeled with vmcnt(0) (vmcnt(8) would not wait there).
// Swizzle: A explicit write-XOR, B source-preswizzle; frag reads XOR (row&7) both.
template <bool SWAP>
__device__ __forceinline__ void gemm_core64_f32A(const float* A, const US* Wt,
                                                 int m0, int n0, US* As, US* Bs,
                                                 f32x4 acc[4][4]) {
  const int tid = threadIdx.x;
  const int wave = tid >> 6, lane = tid & 63;
  const int quad = lane >> 4, l16 = lane & 15;
  const int wm = wave >> 1, wn = wave & 1;
#pragma unroll
  for (int i = 0; i < 4; ++i)
#pragma unroll
    for (int j = 0; j < 4; ++j) acc[i][j] = (f32x4)0.0f;

  const int srow = tid >> 3;                 // 0..31
  const int ca = tid & 7;                    // A logical chunk (coalesced)
  const int scb = ca ^ (srow & 7);           // B pre-swizzled global chunk
  const float* gA = A + (size_t)(m0 + srow) * 1024 + ca * 8;
  const US* gB = Wt + (size_t)(n0 + srow) * 1024 + scb * 8;
  US* lB = Bs + wave * 512;

  float4 fa0[4], fa1[4];
#pragma unroll
  for (int rr = 0; rr < 4; ++rr) {
    fa0[rr] = *(const float4*)(gA + (size_t)rr * 32 * 1024);
    fa1[rr] = *(const float4*)(gA + (size_t)rr * 32 * 1024 + 4);
  }
  asm volatile("" ::: "memory");  // pin prologue A-loads before loop's B-loads

#define QKV_STAGE(k0, PREFETCH)                                                  \
  {                                                                              \
    _Pragma("unroll") for (int c = 0; c < 4; ++c)                                \
        gload16(gB + (size_t)c * 32 * 1024 + (k0), lB + c * 2048);               \
    _Pragma("unroll") for (int rr = 0; rr < 4; ++rr) {                           \
      const int row = srow + rr * 32;                                            \
      uint4 w;                                                                   \
      w.x = pk2(fa0[rr].x, fa0[rr].y);                                           \
      w.y = pk2(fa0[rr].z, fa0[rr].w);                                           \
      w.z = pk2(fa1[rr].x, fa1[rr].y);                                           \
      w.w = pk2(fa1[rr].z, fa1[rr].w);                                           \
      *(uint4*)&As[row * 64 + ((ca ^ (row & 7)) << 3)] = w;                      \
    }                                                                            \
    asm volatile("" ::: "memory"); /* pin: B-loads older than prefetch */        \
    if (PREFETCH) {                                                              \
      _Pragma("unroll") for (int rr = 0; rr < 4; ++rr) {                         \
        fa0[rr] = *(const float4*)(gA + (size_t)rr * 32 * 1024 + (k0) + 64);     \
        fa1[rr] = *(const float4*)(gA + (size_t)rr * 32 * 1024 + (k0) + 68);     \
      }                                                                          \
    }                                                                            \
  }

#define QKV_COMPUTE()                                                            \
  {                                                                              \
    uint4 af[4][2], bf_[4][2];                                                   \
    _Pragma("unroll") for (int mt = 0; mt < 4; ++mt) {                           \
      const int row = wm * 64 + mt * 16 + l16;                                   \
      af[mt][0] = *(const uint4*)&As[row * 64 + ((quad ^ (row & 7)) << 3)];      \
      af[mt][1] = *(const uint4*)&As[row * 64 + (((4 + quad) ^ (row & 7)) << 3)];\
    }                                                                            \
    _Pragma("unroll") for (int nt = 0; nt < 4; ++nt) {                           \
      const int row = wn * 64 + nt * 16 + l16;                                   \
      bf_[nt][0] = *(const uint4*)&Bs[row * 64 + ((quad ^ (row & 7)) << 3)];     \
      bf_[nt][1] = *(const uint4*)&Bs[row * 64 + (((4 + quad) ^ (row & 7)) << 3)];\
    }                                                                            \
    _Pragma("unroll") for (int i = 0; i < 4; ++i)                                \
      _Pragma("unroll") for (int j = 0; j < 4; ++j) {                            \
        if (SWAP) {                                                              \
          acc[i][j] = __builtin_amdgcn_mfma_f32_16x16x32_bf16(                   \
              asb(bf_[i][0]), asb(af[j][0]), acc[i][j], 0, 0, 0);                \
          acc[i][j] = __builtin_amdgcn_mfma_f32_16x16x32_bf16(                   \
              asb(bf_[i][1]), asb(af[j][1]), acc[i][j], 0, 0, 0);                \
        } else {                                                                 \
          acc[i][j] = __builtin_amdgcn_mfma_f32_16x16x32_bf16(                   \
              asb(af[i][0]), asb(bf_[j][0]), acc[i][j], 0, 0, 0);                \
          acc[i][j] = __builtin_amdgcn_mfma_f32_16x16x32_bf16(                   \
              asb(af[i][1]), asb(bf_[j][1]), acc[i][j], 0, 0, 0);                \
        }                                                                        \
      }                                                                          \
  }

  for (int t = 0; t < 15; ++t) {
    QKV_STAGE(t * 64, true);
    asm volatile("s_waitcnt vmcnt(8) lgkmcnt(0)" ::: "memory");
    __builtin_amdgcn_s_barrier();
    QKV_COMPUTE();
    asm volatile("s_waitcnt lgkmcnt(0)" ::: "memory");
    __builtin_amdgcn_s_barrier();
  }
  QKV_STAGE(960, false);
  asm volatile("s_waitcnt vmcnt(0) lgkmcnt(0)" ::: "memory");
  __builtin_amdgcn_s_barrier();
  QKV_COMPUTE();
#undef QKV_STAGE
#undef QKV_COMPUTE
}

// Fused QKV projection (N=3072), A read directly as fp32. Q pre-scaled by log2(e).
__global__ __launch_bounds__(256, 4) void gemm_qkv_kernel(
    const float* __restrict__ q, const float* __restrict__ k, const float* __restrict__ v,
    const US* __restrict__ wfT,
    const float* __restrict__ bq, const float* __restrict__ bk, const float* __restrict__ bv,
    US* __restrict__ qh, US* __restrict__ kh, US* __restrict__ vt) {
  __shared__ __align__(16) US As[8192], Bs[8192];  // [128][64] each, 32 KB total
  const int m0 = blockIdx.x * 128, n0 = blockIdx.y * 128;
  const int which = n0 >> 10;
  const int nl0 = n0 & 1023;
  const float* A = (which == 0) ? q : (which == 1) ? k : v;
  const float* bias = (which == 0) ? bq : (which == 1) ? bk : bv;
  const int tid = threadIdx.x, wave = tid >> 6, lane = tid & 63;
  const int quad = lane >> 4, l16 = lane & 15;
  const int wm = wave >> 1, wn = wave & 1;
  f32x4 acc[4][4];
  if (which == 2) {
    gemm_core64_f32A<true>(A, wfT, m0, n0, As, Bs, acc);
#pragma unroll
    for (int nt = 0; nt < 4; ++nt) {
      int dg = nl0 + wn * 64 + nt * 16 + quad * 4;
#pragma unroll
      for (int r = 0; r < 4; ++r) {
        int d = dg + r;
        float bval = bias[d];
        int hh = d >> 6, dd = d & 63;
#pragma unroll
        for (int mt = 0; mt < 4; ++mt) {
          int sg = m0 + wm * 64 + mt * 16;
          int bb = sg >> 11, ss = sg & 2047;
          vt[(((size_t)bb * 16 + hh) * 64 + dd) * 2048 + ss + l16] =
              f2bf(acc[nt][mt][r] + bval);
        }
      }
    }
  } else {
    gemm_core64_f32A<false>(A, wfT, m0, n0, As, Bs, acc);
    US* O = (which == 0) ? qh : kh;
    const float scale = (which == 0) ? LOG2E : 1.0f;
#pragma unroll
    for (int nt = 0; nt < 4; ++nt) {
      int nl = nl0 + wn * 64 + nt * 16 + l16;
      float bval = bias[nl];
      int hh = nl >> 6, d = nl & 63;
#pragma unroll
      for (int mt = 0; mt < 4; ++mt) {
#pragma unroll
        for (int r = 0; r < 4; ++r) {
          int m = m0 + wm * 64 + mt * 16 + quad * 4 + r;
          int bb = m >> 11, s = m & 2047;
          O[((bb * 16 + hh) * 2048 + s) * 64 + d] = f2bf((acc[mt][nt][r] + bval) * scale);
        }
      }
    }
  }
}

// Output projection: ao bf16 [4096][1024] @ woT + bo -> fp32 out. 128x64 tile, BK=64.
__global__ __launch_bounds__(256, 4) void gemm_out_kernel(
    const US* __restrict__ ao, const US* __restrict__ woT,
    const float* __restrict__ bo, float* __restrict__ out) {
  __shared__ __align__(16) US As[8192], Bs[4096];  // A [128][64], B [64][64]
  const int m0 = blockIdx.x * 128, n0 = blockIdx.y * 64;
  const int tid = threadIdx.x;
  const int wave = tid >> 6, lane = tid & 63;
  const int quad = lane >> 4, l16 = lane & 15;
  f32x4 acc[2][4];
#pragma unroll
  for (int i = 0; i < 2; ++i)
#pragma unroll
    for (int j = 0; j < 4; ++j) acc[i][j] = (f32x4)0.0f;

  const int srow = tid >> 3;
  const int sch = (tid & 7) ^ (srow & 7);
  const US* gA = ao + (size_t)(m0 + srow) * 1024 + sch * 8;
  const US* gB = woT + (size_t)(n0 + srow) * 1024 + sch * 8;
  US* lA = As + wave * 512;
  US* lB = Bs + wave * 512;

  for (int k0 = 0; k0 < 1024; k0 += 64) {
#pragma unroll
    for (int c = 0; c < 4; ++c)
      gload16(gA + (size_t)c * 32 * 1024 + k0, lA + c * 2048);
#pragma unroll
    for (int c = 0; c < 2; ++c)
      gload16(gB + (size_t)c * 32 * 1024 + k0, lB + c * 2048);
    __syncthreads();
    uint4 af[2][2], bf_[4][2];
#pragma unroll
    for (int mt = 0; mt < 2; ++mt) {
      const int row = wave * 32 + mt * 16 + l16;
      af[mt][0] = *(const uint4*)&As[row * 64 + ((quad ^ (row & 7)) << 3)];
      af[mt][1] = *(const uint4*)&As[row * 64 + (((4 + quad) ^ (row & 7)) << 3)];
    }
#pragma unroll
    for (int nt = 0; nt < 4; ++nt) {
      const int row = nt * 16 + l16;
      bf_[nt][0] = *(const uint4*)&Bs[row * 64 + ((quad ^ (row & 7)) << 3)];
      bf_[nt][1] = *(const uint4*)&Bs[row * 64 + (((4 + quad) ^ (row & 7)) << 3)];
    }
#pragma unroll
    for (int mt = 0; mt < 2; ++mt)
#pragma unroll
      for (int nt = 0; nt < 4; ++nt) {
        acc[mt][nt] = __builtin_amdgcn_mfma_f32_16x16x32_bf16(asb(af[mt][0]), asb(bf_[nt][0]),
                                                              acc[mt][nt], 0, 0, 0);
        acc[mt][nt] = __builtin_amdgcn_mfma_f32_16x16x32_bf16(asb(af[mt][1]), asb(bf_[nt][1]),
                                                              acc[mt][nt], 0, 0, 0);
      }
    __syncthreads();
  }
#pragma unroll
  for (int nt = 0; nt < 4; ++nt) {
    int n = n0 + nt * 16 + l16;
    float bval = bo[n];
#pragma unroll
    for (int mt = 0; mt < 2; ++mt) {
#pragma unroll
      for (int r = 0; r < 4; ++r) {
        int m = m0 + wave * 32 + mt * 16 + quad * 4 + r;
        out[m * 1024 + n] = acc[mt][nt][r] + bval;
      }
    }
  }
}

// ------------- causal attention: 512 thr (8 waves), S^T/O^T form, 128 keys/iter ------
__global__ __launch_bounds__(512, 2) void attn_kernel(
    const US* __restrict__ qh, const US* __restrict__ kh,
    const US* __restrict__ vt, US* __restrict__ aout) {
  __shared__ __align__(16) char arena[73728];
  US* KsA = (US*)arena;
  US* VsA = (US*)(arena + 32768);
  US* Qs  = (US*)(arena + 65536);
  float* Oex = (float*)arena;                  // [4][64][68]
  float* lEx = (float*)(arena + 69632);        // [4][64]

  const int tid = threadIdx.x;
  const int wave = tid >> 6, lane = tid & 63;
  const int l31 = lane & 31, lh = lane >> 5;
  const int w_m = wave & 1, w_k = wave >> 1;   // w_k in 0..3
  const int bh = blockIdx.x;
  const int b = bh >> 4, h = bh & 15;
  const int jg = blockIdx.y;

  const US* gkb = kh + (size_t)bh * 2048 * 64;
  const US* gvb = vt + (size_t)bh * 64 * 2048;

  for (int ei = 0; ei < 2; ++ei) {
    const int qt = ei ? jg : (31 - jg);
    const int q0 = qt * 64;
    const int nit = (qt >> 1) + 1;   // 128-key pair iterations
    __syncthreads();  // previous tile's epilogue reads / buffer reuse
    {
      const US* gq = qh + ((size_t)bh * 2048 + q0) * 64;
      {
        int p = tid;
        int row = p >> 3, c = (p & 7) ^ (row & 7);
        gload16(gq + row * 64 + c * 8, Qs + wave * 512);
      }
#pragma unroll
      for (int ro = 0; ro < 2; ++ro) {
        int p = tid + ro * 512;
        int row = p >> 3, c = (p & 7) ^ (row & 7);
        gload16(gkb + row * 64 + c * 8, KsA + ro * 4096 + wave * 512);
      }
#pragma unroll
      for (int ro = 0; ro < 2; ++ro) {
        int p = tid + ro * 512;
        int row = p >> 4, c = (p & 15) ^ (row & 15);
        gload16(gvb + row * 2048 + c * 8, VsA + ro * 4096 + wave * 512);
      }
    }
    __syncthreads();

    const int qrow = w_m * 32 + l31;
    uint4 bq[4];
#pragma unroll
    for (int s = 0; s < 4; ++s)
      bq[s] = *(const uint4*)&Qs[qrow * 64 + (((2 * s + lh) ^ (qrow & 7)) * 8)];
    const int q_g = q0 + qrow;

    float l_lane = 0.0f;
    f32x16 Oa0 = (f32x16)0.0f, Oa1 = (f32x16)0.0f;

    for (int it = 0; it < nit; ++it) {
      const int cb = it & 1;
      const int kb = it * 128;
      if (it) __syncthreads();
      if (it + 1 < nit) {
        const US* gk = gkb + (kb + 128) * 64;
        const US* gv = gvb + (kb + 128);
        US* kd = KsA + (cb ^ 1) * 8192;
        US* vd = VsA + (cb ^ 1) * 8192;
#pragma unroll
        for (int ro = 0; ro < 2; ++ro) {
          int p = tid + ro * 512;
          int row = p >> 3, c = (p & 7) ^ (row & 7);
          gload16(gk + row * 64 + c * 8, kd + ro * 4096 + wave * 512);
        }
#pragma unroll
        for (int ro = 0; ro < 2; ++ro) {
          int p = tid + ro * 512;
          int row = p >> 4, c = (p & 15) ^ (row & 15);
          gload16(gv + row * 2048 + c * 8, vd + ro * 4096 + wave * 512);
        }
      }
      const US* Kc = KsA + cb * 8192;
      const US* Vc = VsA + cb * 8192;

      f32x16 sa0 = (f32x16)0.0f;
      const int kr0 = w_k * 32 + l31;
#pragma unroll
      for (int s = 0; s < 4; ++s) {
        uint4 ka0 = *(const uint4*)&Kc[kr0 * 64 + (((2 * s + lh) ^ (kr0 & 7)) * 8)];
        sa0 = __builtin_amdgcn_mfma_f32_32x32x16_bf16(asb(ka0), asb(bq[s]), sa0, 0, 0, 0);
      }

      const bool diag = (it == nit - 1);
      float e[16];
      const int kbase = kb + w_k * 32 + 4 * lh;
#pragma unroll
      for (int r = 0; r < 16; ++r) {
        float ev = __builtin_amdgcn_exp2f(sa0[r]);
        if (diag) {
          int key_g = kbase + (r & 3) + 8 * (r >> 2);
          if (key_g > q_g) ev = 0.0f;
        }
        e[r] = ev;
        l_lane += ev;
      }

      // P^T B-frags via half-wave exchange (2 shuffles per s2: each lane only needs
      // the cross-half words of ONE operand pair, so pre-select lh?PA:PB then swap).
#pragma unroll
      for (int s2 = 0; s2 < 2; ++s2) {
        uint32_t PA0 = pk2(e[8 * s2 + 0], e[8 * s2 + 1]);
        uint32_t PA1 = pk2(e[8 * s2 + 2], e[8 * s2 + 3]);
        uint32_t PB0 = pk2(e[8 * s2 + 4], e[8 * s2 + 5]);
        uint32_t PB1 = pk2(e[8 * s2 + 6], e[8 * s2 + 7]);
        uint32_t W0 = (uint32_t)__shfl_xor((int)(lh ? PA0 : PB0), 32, 64);
        uint32_t W1 = (uint32_t)__shfl_xor((int)(lh ? PA1 : PB1), 32, 64);
        uint4 bp;
        bp.x = lh ? W0 : PA0;
        bp.y = lh ? W1 : PA1;
        bp.z = lh ? PB0 : W0;
        bp.w = lh ? PB1 : W1;
        const int c_log = w_k * 4 + s2 * 2 + lh;
        int vr0 = l31;
        uint4 va0 = *(const uint4*)&Vc[vr0 * 128 + ((c_log ^ (vr0 & 15)) * 8)];
        Oa0 = __builtin_amdgcn_mfma_f32_32x32x16_bf16(asb(va0), asb(bp), Oa0, 0, 0, 0);
        int vr1 = 32 + l31;
        uint4 va1 = *(const uint4*)&Vc[vr1 * 128 + ((c_log ^ (vr1 & 15)) * 8)];
        Oa1 = __builtin_amdgcn_mfma_f32_32x32x16_bf16(asb(va1), asb(bp), Oa1, 0, 0, 0);
      }
    }

    float l_q = l_lane + __shfl_xor(l_lane, 32, 64);

    __syncthreads();  // K/V buffers dead; overlay epilogue exchange
    {
      float* myO = Oex + w_k * (64 * 68);
      int q_idx = w_m * 32 + l31;
#pragma unroll
      for (int r = 0; r < 16; ++r) {
        int dr = 4 * lh + (r & 3) + 8 * (r >> 2);
        myO[q_idx * 68 + dr] = Oa0[r];
        myO[q_idx * 68 + 32 + dr] = Oa1[r];
      }
      if (lh == 0) lEx[w_k * 64 + q_idx] = l_q;
    }
    __syncthreads();
    {
      int q_idx = tid >> 3;
      int dseg = (tid & 7) * 8;
      float inv = 1.0f / (lEx[q_idx] + lEx[64 + q_idx] + lEx[128 + q_idx] + lEx[192 + q_idx]);
      union { US s[8]; uint4 v; } ob;
#pragma unroll
      for (int t2 = 0; t2 < 8; ++t2) {
        float o = Oex[q_idx * 68 + dseg + t2]
                + Oex[64 * 68 + q_idx * 68 + dseg + t2]
                + Oex[2 * 64 * 68 + q_idx * 68 + dseg + t2]
                + Oex[3 * 64 * 68 + q_idx * 68 + dseg + t2];
        ob.s[t2] = f2bf(o * inv);
      }
      US* dst = aout + ((size_t)b * 2048 + q0 + q_idx) * 1024 + h * 64 + dseg;
      *(uint4*)dst = ob.v;
    }
  }
}

extern "C" void kernel_launch(void* const* d_in, const int* in_sizes, int n_in,
                              void* d_out, int out_size, void* d_ws, size_t ws_size,
                              hipStream_t stream) {
  const float* q  = (const float*)d_in[0];
  const float* k  = (const float*)d_in[1];
  const float* v  = (const float*)d_in[2];
  const float* wq = (const float*)d_in[3];
  const float* bq = (const float*)d_in[4];
  const float* wk = (const float*)d_in[5];
  const float* bk = (const float*)d_in[6];
  const float* wv = (const float*)d_in[7];
  const float* bv = (const float*)d_in[8];
  const float* wo = (const float*)d_in[9];
  const float* bo = (const float*)d_in[10];
  float* out = (float*)d_out;

  char* ws = (char*)d_ws;
  const size_t MB = 1024 * 1024;
  US* wqT = (US*)(ws + 24 * MB);  // wqT/wkT/wvT contiguous -> fused [3072][1024]
  US* wkT = (US*)(ws + 26 * MB);
  US* wvT = (US*)(ws + 28 * MB);
  US* woT = (US*)(ws + 30 * MB);
  US* qh  = (US*)(ws + 32 * MB);  // [B,H,S,D] (pre-scaled by log2e)
  US* kh  = (US*)(ws + 40 * MB);  // [B,H,S,D]
  US* vt  = (US*)(ws + 48 * MB);  // [B,H,D,S]
  US* ao  = (US*)(ws + 56 * MB);  // [B*S, 1024]

  prep_kernel<<<1024, 256, 0, stream>>>(wq, wk, wv, wo, wqT, wkT, wvT, woT);
  gemm_qkv_kernel<<<dim3(32, 24), 256, 0, stream>>>(q, k, v, wqT,
                                                    bq, bk, bv, qh, kh, vt);
  attn_kernel<<<dim3(32, 16), 512, 0, stream>>>(qh, kh, vt, ao);
  gemm_out_kernel<<<dim3(32, 16), 256, 0, stream>>>(ao, woT, bo, out);
}

// Round 10
// 197.644 us; speedup vs baseline: 1.1154x; 1.1154x over previous
//
#include <hip/hip_runtime.h>
#include <stdint.h>

#define AS1q __attribute__((address_space(1)))
#define AS3q __attribute__((address_space(3)))

typedef unsigned short US;
typedef __bf16 bf16x8 __attribute__((ext_vector_type(8)));
typedef float f32x4 __attribute__((ext_vector_type(4)));
typedef float f32x16 __attribute__((ext_vector_type(16)));
typedef float f32x2 __attribute__((ext_vector_type(2)));
typedef __bf16 bf16x2 __attribute__((ext_vector_type(2)));

#define LOG2E 1.44269504088896340736f

__device__ __forceinline__ US f2bf(float f) {
  union { float f; uint32_t u; } c; c.f = f;
  uint32_t u = c.u;
  return (US)((u + 0x7fffu + ((u >> 16) & 1u)) >> 16);
}

__device__ __forceinline__ bf16x8 asb(uint4 u) {
  union { uint4 u; bf16x8 b; } c; c.u = u; return c.b;
}

__device__ __forceinline__ uint32_t pk2(float a, float b) {
  f32x2 fv; fv[0] = a; fv[1] = b;
  bf16x2 bb = __builtin_convertvector(fv, bf16x2);
  union { bf16x2 b; uint32_t u; } c; c.b = bb; return c.u;
}

__device__ __forceinline__ void gload16(const void* g, void* l) {
  __builtin_amdgcn_global_load_lds((AS1q void*)(void*)g, (AS3q void*)l, 16, 0, 0);
}

// ------------- prep: fused q/k/v fp32->bf16 + 4 weight transposes -------------
__global__ void prep_kernel(const float* __restrict__ q, const float* __restrict__ k,
                            const float* __restrict__ v,
                            const float* __restrict__ w0, const float* __restrict__ w1,
                            const float* __restrict__ w2, const float* __restrict__ w3,
                            US* __restrict__ qb, US* __restrict__ kb, US* __restrict__ vb,
                            US* __restrict__ t0, US* __restrict__ t1,
                            US* __restrict__ t2, US* __restrict__ t3) {
  __shared__ US T[64 * 68];
  const int bx = blockIdx.x;
  const int t = threadIdx.x;
  if (bx < 6144) {
    const int ten = bx >> 11, chunk = bx & 2047;
    const float* s; US* d;
    if (ten == 0)      { s = q; d = qb; }
    else if (ten == 1) { s = k; d = kb; }
    else               { s = v; d = vb; }
    int i = (chunk * 256 + t) * 8;
    float4 f0 = *(const float4*)&s[i];
    float4 f1 = *(const float4*)&s[i + 4];
    ushort4 u0, u1;
    u0.x = f2bf(f0.x); u0.y = f2bf(f0.y); u0.z = f2bf(f0.z); u0.w = f2bf(f0.w);
    u1.x = f2bf(f1.x); u1.y = f2bf(f1.y); u1.z = f2bf(f1.z); u1.w = f2bf(f1.w);
    *(ushort4*)&d[i] = u0;
    *(ushort4*)&d[i + 4] = u1;
    return;
  }
  const int idx = bx - 6144;
  const int wsel = idx >> 8, rem = idx & 255;
  const int n0 = (rem & 15) * 64, k0 = (rem >> 4) * 64;
  const float* W; US* Wt;
  if (wsel == 0)      { W = w0; Wt = t0; }
  else if (wsel == 1) { W = w1; Wt = t1; }
  else if (wsel == 2) { W = w2; Wt = t2; }
  else                { W = w3; Wt = t3; }
#pragma unroll
  for (int it = 0; it < 4; ++it) {
    int p = t + it * 256;
    int row = p >> 4, c4 = (p & 15) * 4;
    float4 f = *(const float4*)&W[(k0 + row) * 1024 + n0 + c4];
    ushort4 u;
    u.x = f2bf(f.x); u.y = f2bf(f.y); u.z = f2bf(f.z); u.w = f2bf(f.w);
    *(ushort4*)&T[row * 68 + c4] = u;
  }
  __syncthreads();
#pragma unroll
  for (int it = 0; it < 4; ++it) {
    int p = t + it * 256;
    int rn = p >> 4, ck = (p & 15) * 4;
    ushort4 o;
    o.x = T[(ck + 0) * 68 + rn];
    o.y = T[(ck + 1) * 68 + rn];
    o.z = T[(ck + 2) * 68 + rn];
    o.w = T[(ck + 3) * 68 + rn];
    *(ushort4*)&Wt[(n0 + rn) * 1024 + k0 + ck] = o;
  }
}

// ------------- GEMM core: 128x128 tile, BK=64, XOR-swizzled LDS, 2-phase ------------
// Staging: pre-swizzled global source + linear global_load_lds dest (rule #21):
// thread t writes 16B at LDS elem t*8 -> row t>>3 (+32c), physical chunk t&7;
// global source chunk = (t&7) ^ (row&7), so logical chunk q of row r sits at
// physical chunk q^(r&7). Frag reads XOR the same way -> 0 bank conflicts (R2-proven).
// BK=64 halves the barrier-pairs + vmcnt(0) drains vs BK=32 (32 MFMA per pair).
template <bool SWAP>
__device__ __forceinline__ void gemm_core64(const US* A, const US* Wt,
                                            int m0, int n0, US* As, US* Bs,
                                            f32x4 acc[4][4]) {
  const int tid = threadIdx.x;
  const int wave = tid >> 6, lane = tid & 63;
  const int quad = lane >> 4, l16 = lane & 15;
  const int wm = wave >> 1, wn = wave & 1;
#pragma unroll
  for (int i = 0; i < 4; ++i)
#pragma unroll
    for (int j = 0; j < 4; ++j) acc[i][j] = (f32x4)0.0f;

  const int srow = tid >> 3;                 // 0..31
  const int sch = (tid & 7) ^ (srow & 7);    // pre-swizzled global chunk
  const US* gA = A + (size_t)(m0 + srow) * 1024 + sch * 8;
  const US* gB = Wt + (size_t)(n0 + srow) * 1024 + sch * 8;
  US* lA = As + wave * 512;
  US* lB = Bs + wave * 512;

  for (int k0 = 0; k0 < 1024; k0 += 64) {
#pragma unroll
    for (int c = 0; c < 4; ++c) {
      gload16(gA + (size_t)c * 32 * 1024 + k0, lA + c * 2048);
      gload16(gB + (size_t)c * 32 * 1024 + k0, lB + c * 2048);
    }
    __syncthreads();
    uint4 af[4][2], bf_[4][2];
#pragma unroll
    for (int mt = 0; mt < 4; ++mt) {
      const int row = wm * 64 + mt * 16 + l16;
      af[mt][0] = *(const uint4*)&As[row * 64 + ((quad ^ (row & 7)) << 3)];
      af[mt][1] = *(const uint4*)&As[row * 64 + (((4 + quad) ^ (row & 7)) << 3)];
    }
#pragma unroll
    for (int nt = 0; nt < 4; ++nt) {
      const int row = wn * 64 + nt * 16 + l16;
      bf_[nt][0] = *(const uint4*)&Bs[row * 64 + ((quad ^ (row & 7)) << 3)];
      bf_[nt][1] = *(const uint4*)&Bs[row * 64 + (((4 + quad) ^ (row & 7)) << 3)];
    }
#pragma unroll
    for (int i = 0; i < 4; ++i)
#pragma unroll
      for (int j = 0; j < 4; ++j) {
        if (SWAP) {
          acc[i][j] = __builtin_amdgcn_mfma_f32_16x16x32_bf16(asb(bf_[i][0]), asb(af[j][0]),
                                                              acc[i][j], 0, 0, 0);
          acc[i][j] = __builtin_amdgcn_mfma_f32_16x16x32_bf16(asb(bf_[i][1]), asb(af[j][1]),
                                                              acc[i][j], 0, 0, 0);
        } else {
          acc[i][j] = __builtin_amdgcn_mfma_f32_16x16x32_bf16(asb(af[i][0]), asb(bf_[j][0]),
                                                              acc[i][j], 0, 0, 0);
          acc[i][j] = __builtin_amdgcn_mfma_f32_16x16x32_bf16(asb(af[i][1]), asb(bf_[j][1]),
                                                              acc[i][j], 0, 0, 0);
        }
      }
    __syncthreads();
  }
}

// Fused QKV projection (N=3072). Q is scaled by log2(e) so attn can use raw exp2.
__global__ __launch_bounds__(256, 4) void gemm_qkv_kernel(
    const US* __restrict__ qb, const US* __restrict__ kb, const US* __restrict__ vb,
    const US* __restrict__ wfT,
    const float* __restrict__ bq, const float* __restrict__ bk, const float* __restrict__ bv,
    US* __restrict__ qh, US* __restrict__ kh, US* __restrict__ vt) {
  __shared__ __align__(16) US As[8192], Bs[8192];  // [128][64] each, 32 KB total
  const int m0 = blockIdx.x * 128, n0 = blockIdx.y * 128;
  const int which = n0 >> 10;
  const int nl0 = n0 & 1023;
  const US* A = (which == 0) ? qb : (which == 1) ? kb : vb;
  const float* bias = (which == 0) ? bq : (which == 1) ? bk : bv;
  const int tid = threadIdx.x, wave = tid >> 6, lane = tid & 63;
  const int quad = lane >> 4, l16 = lane & 15;
  const int wm = wave >> 1, wn = wave & 1;
  f32x4 acc[4][4];
  if (which == 2) {
    gemm_core64<true>(A, wfT, m0, n0, As, Bs, acc);
#pragma unroll
    for (int nt = 0; nt < 4; ++nt) {
      int dg = nl0 + wn * 64 + nt * 16 + quad * 4;
#pragma unroll
      for (int r = 0; r < 4; ++r) {
        int d = dg + r;
        float bval = bias[d];
        int hh = d >> 6, dd = d & 63;
#pragma unroll
        for (int mt = 0; mt < 4; ++mt) {
          int sg = m0 + wm * 64 + mt * 16;
          int bb = sg >> 11, ss = sg & 2047;
          vt[(((size_t)bb * 16 + hh) * 64 + dd) * 2048 + ss + l16] =
              f2bf(acc[nt][mt][r] + bval);
        }
      }
    }
  } else {
    gemm_core64<false>(A, wfT, m0, n0, As, Bs, acc);
    US* O = (which == 0) ? qh : kh;
    const float scale = (which == 0) ? LOG2E : 1.0f;
#pragma unroll
    for (int nt = 0; nt < 4; ++nt) {
      int nl = nl0 + wn * 64 + nt * 16 + l16;
      float bval = bias[nl];
      int hh = nl >> 6, d = nl & 63;
#pragma unroll
      for (int mt = 0; mt < 4; ++mt) {
#pragma unroll
        for (int r = 0; r < 4; ++r) {
          int m = m0 + wm * 64 + mt * 16 + quad * 4 + r;
          int bb = m >> 11, s = m & 2047;
          O[((bb * 16 + hh) * 2048 + s) * 64 + d] = f2bf((acc[mt][nt][r] + bval) * scale);
        }
      }
    }
  }
}

// Output projection: ao bf16 [4096][1024] @ woT + bo -> fp32 out. 128x64 tile, BK=64.
__global__ __launch_bounds__(256, 4) void gemm_out_kernel(
    const US* __restrict__ ao, const US* __restrict__ woT,
    const float* __restrict__ bo, float* __restrict__ out) {
  __shared__ __align__(16) US As[8192], Bs[4096];  // A [128][64], B [64][64]
  const int m0 = blockIdx.x * 128, n0 = blockIdx.y * 64;
  const int tid = threadIdx.x;
  const int wave = tid >> 6, lane = tid & 63;
  const int quad = lane >> 4, l16 = lane & 15;
  f32x4 acc[2][4];
#pragma unroll
  for (int i = 0; i < 2; ++i)
#pragma unroll
    for (int j = 0; j < 4; ++j) acc[i][j] = (f32x4)0.0f;

  const int srow = tid >> 3;
  const int sch = (tid & 7) ^ (srow & 7);
  const US* gA = ao + (size_t)(m0 + srow) * 1024 + sch * 8;
  const US* gB = woT + (size_t)(n0 + srow) * 1024 + sch * 8;
  US* lA = As + wave * 512;
  US* lB = Bs + wave * 512;

  for (int k0 = 0; k0 < 1024; k0 += 64) {
#pragma unroll
    for (int c = 0; c < 4; ++c)
      gload16(gA + (size_t)c * 32 * 1024 + k0, lA + c * 2048);
#pragma unroll
    for (int c = 0; c < 2; ++c)
      gload16(gB + (size_t)c * 32 * 1024 + k0, lB + c * 2048);
    __syncthreads();
    uint4 af[2][2], bf_[4][2];
#pragma unroll
    for (int mt = 0; mt < 2; ++mt) {
      const int row = wave * 32 + mt * 16 + l16;
      af[mt][0] = *(const uint4*)&As[row * 64 + ((quad ^ (row & 7)) << 3)];
      af[mt][1] = *(const uint4*)&As[row * 64 + (((4 + quad) ^ (row & 7)) << 3)];
    }
#pragma unroll
    for (int nt = 0; nt < 4; ++nt) {
      const int row = nt * 16 + l16;
      bf_[nt][0] = *(const uint4*)&Bs[row * 64 + ((quad ^ (row & 7)) << 3)];
      bf_[nt][1] = *(const uint4*)&Bs[row * 64 + (((4 + quad) ^ (row & 7)) << 3)];
    }
#pragma unroll
    for (int mt = 0; mt < 2; ++mt)
#pragma unroll
      for (int nt = 0; nt < 4; ++nt) {
        acc[mt][nt] = __builtin_amdgcn_mfma_f32_16x16x32_bf16(asb(af[mt][0]), asb(bf_[nt][0]),
                                                              acc[mt][nt], 0, 0, 0);
        acc[mt][nt] = __builtin_amdgcn_mfma_f32_16x16x32_bf16(asb(af[mt][1]), asb(bf_[nt][1]),
                                                              acc[mt][nt], 0, 0, 0);
      }
    __syncthreads();
  }
#pragma unroll
  for (int nt = 0; nt < 4; ++nt) {
    int n = n0 + nt * 16 + l16;
    float bval = bo[n];
#pragma unroll
    for (int mt = 0; mt < 2; ++mt) {
#pragma unroll
      for (int r = 0; r < 4; ++r) {
        int m = m0 + wave * 32 + mt * 16 + quad * 4 + r;
        out[m * 1024 + n] = acc[mt][nt][r] + bval;
      }
    }
  }
}

// ------------- causal attention: 512 thr (8 waves), S^T/O^T form, 128 keys/iter ------
__global__ __launch_bounds__(512, 2) void attn_kernel(
    const US* __restrict__ qh, const US* __restrict__ kh,
    const US* __restrict__ vt, US* __restrict__ aout) {
  __shared__ __align__(16) char arena[73728];
  US* KsA = (US*)arena;
  US* VsA = (US*)(arena + 32768);
  US* Qs  = (US*)(arena + 65536);
  float* Oex = (float*)arena;                  // [4][64][68]
  float* lEx = (float*)(arena + 69632);        // [4][64]

  const int tid = threadIdx.x;
  const int wave = tid >> 6, lane = tid & 63;
  const int l31 = lane & 31, lh = lane >> 5;
  const int w_m = wave & 1, w_k = wave >> 1;   // w_k in 0..3
  const int bh = blockIdx.x;
  const int b = bh >> 4, h = bh & 15;
  const int jg = blockIdx.y;

  const US* gkb = kh + (size_t)bh * 2048 * 64;
  const US* gvb = vt + (size_t)bh * 64 * 2048;

  for (int ei = 0; ei < 2; ++ei) {
    const int qt = ei ? jg : (31 - jg);
    const int q0 = qt * 64;
    const int nit = (qt >> 1) + 1;   // 128-key pair iterations
    __syncthreads();  // previous tile's epilogue reads / buffer reuse
    {
      const US* gq = qh + ((size_t)bh * 2048 + q0) * 64;
      {
        int p = tid;
        int row = p >> 3, c = (p & 7) ^ (row & 7);
        gload16(gq + row * 64 + c * 8, Qs + wave * 512);
      }
#pragma unroll
      for (int ro = 0; ro < 2; ++ro) {
        int p = tid + ro * 512;
        int row = p >> 3, c = (p & 7) ^ (row & 7);
        gload16(gkb + row * 64 + c * 8, KsA + ro * 4096 + wave * 512);
      }
#pragma unroll
      for (int ro = 0; ro < 2; ++ro) {
        int p = tid + ro * 512;
        int row = p >> 4, c = (p & 15) ^ (row & 15);
        gload16(gvb + row * 2048 + c * 8, VsA + ro * 4096 + wave * 512);
      }
    }
    __syncthreads();

    const int qrow = w_m * 32 + l31;
    uint4 bq[4];
#pragma unroll
    for (int s = 0; s < 4; ++s)
      bq[s] = *(const uint4*)&Qs[qrow * 64 + (((2 * s + lh) ^ (qrow & 7)) * 8)];
    const int q_g = q0 + qrow;

    float l_lane = 0.0f;
    f32x16 Oa0 = (f32x16)0.0f, Oa1 = (f32x16)0.0f;

    for (int it = 0; it < nit; ++it) {
      const int cb = it & 1;
      const int kb = it * 128;
      if (it) __syncthreads();
      if (it + 1 < nit) {
        const US* gk = gkb + (kb + 128) * 64;
        const US* gv = gvb + (kb + 128);
        US* kd = KsA + (cb ^ 1) * 8192;
        US* vd = VsA + (cb ^ 1) * 8192;
#pragma unroll
        for (int ro = 0; ro < 2; ++ro) {
          int p = tid + ro * 512;
          int row = p >> 3, c = (p & 7) ^ (row & 7);
          gload16(gk + row * 64 + c * 8, kd + ro * 4096 + wave * 512);
        }
#pragma unroll
        for (int ro = 0; ro < 2; ++ro) {
          int p = tid + ro * 512;
          int row = p >> 4, c = (p & 15) ^ (row & 15);
          gload16(gv + row * 2048 + c * 8, vd + ro * 4096 + wave * 512);
        }
      }
      const US* Kc = KsA + cb * 8192;
      const US* Vc = VsA + cb * 8192;

      f32x16 sa0 = (f32x16)0.0f;
      const int kr0 = w_k * 32 + l31;
#pragma unroll
      for (int s = 0; s < 4; ++s) {
        uint4 ka0 = *(const uint4*)&Kc[kr0 * 64 + (((2 * s + lh) ^ (kr0 & 7)) * 8)];
        sa0 = __builtin_amdgcn_mfma_f32_32x32x16_bf16(asb(ka0), asb(bq[s]), sa0, 0, 0, 0);
      }

      const bool diag = (it == nit - 1);
      float e[16];
      const int kbase = kb + w_k * 32 + 4 * lh;
#pragma unroll
      for (int r = 0; r < 16; ++r) {
        float ev = __builtin_amdgcn_exp2f(sa0[r]);
        if (diag) {
          int key_g = kbase + (r & 3) + 8 * (r >> 2);
          if (key_g > q_g) ev = 0.0f;
        }
        e[r] = ev;
        l_lane += ev;
      }

      // P^T B-frags via half-wave exchange (2 shuffles per s2: each lane only needs
      // the cross-half words of ONE operand pair, so pre-select lh?PA:PB then swap).
#pragma unroll
      for (int s2 = 0; s2 < 2; ++s2) {
        uint32_t PA0 = pk2(e[8 * s2 + 0], e[8 * s2 + 1]);
        uint32_t PA1 = pk2(e[8 * s2 + 2], e[8 * s2 + 3]);
        uint32_t PB0 = pk2(e[8 * s2 + 4], e[8 * s2 + 5]);
        uint32_t PB1 = pk2(e[8 * s2 + 6], e[8 * s2 + 7]);
        uint32_t W0 = (uint32_t)__shfl_xor((int)(lh ? PA0 : PB0), 32, 64);
        uint32_t W1 = (uint32_t)__shfl_xor((int)(lh ? PA1 : PB1), 32, 64);
        uint4 bp;
        bp.x = lh ? W0 : PA0;
        bp.y = lh ? W1 : PA1;
        bp.z = lh ? PB0 : W0;
        bp.w = lh ? PB1 : W1;
        const int c_log = w_k * 4 + s2 * 2 + lh;
        int vr0 = l31;
        uint4 va0 = *(const uint4*)&Vc[vr0 * 128 + ((c_log ^ (vr0 & 15)) * 8)];
        Oa0 = __builtin_amdgcn_mfma_f32_32x32x16_bf16(asb(va0), asb(bp), Oa0, 0, 0, 0);
        int vr1 = 32 + l31;
        uint4 va1 = *(const uint4*)&Vc[vr1 * 128 + ((c_log ^ (vr1 & 15)) * 8)];
        Oa1 = __builtin_amdgcn_mfma_f32_32x32x16_bf16(asb(va1), asb(bp), Oa1, 0, 0, 0);
      }
    }

    float l_q = l_lane + __shfl_xor(l_lane, 32, 64);

    __syncthreads();  // K/V buffers dead; overlay epilogue exchange
    {
      float* myO = Oex + w_k * (64 * 68);
      int q_idx = w_m * 32 + l31;
#pragma unroll
      for (int r = 0; r < 16; ++r) {
        int dr = 4 * lh + (r & 3) + 8 * (r >> 2);
        myO[q_idx * 68 + dr] = Oa0[r];
        myO[q_idx * 68 + 32 + dr] = Oa1[r];
      }
      if (lh == 0) lEx[w_k * 64 + q_idx] = l_q;
    }
    __syncthreads();
    {
      int q_idx = tid >> 3;
      int dseg = (tid & 7) * 8;
      float inv = 1.0f / (lEx[q_idx] + lEx[64 + q_idx] + lEx[128 + q_idx] + lEx[192 + q_idx]);
      union { US s[8]; uint4 v; } ob;
#pragma unroll
      for (int t2 = 0; t2 < 8; ++t2) {
        float o = Oex[q_idx * 68 + dseg + t2]
                + Oex[64 * 68 + q_idx * 68 + dseg + t2]
                + Oex[2 * 64 * 68 + q_idx * 68 + dseg + t2]
                + Oex[3 * 64 * 68 + q_idx * 68 + dseg + t2];
        ob.s[t2] = f2bf(o * inv);
      }
      US* dst = aout + ((size_t)b * 2048 + q0 + q_idx) * 1024 + h * 64 + dseg;
      *(uint4*)dst = ob.v;
    }
  }
}

extern "C" void kernel_launch(void* const* d_in, const int* in_sizes, int n_in,
                              void* d_out, int out_size, void* d_ws, size_t ws_size,
                              hipStream_t stream) {
  const float* q  = (const float*)d_in[0];
  const float* k  = (const float*)d_in[1];
  const float* v  = (const float*)d_in[2];
  const float* wq = (const float*)d_in[3];
  const float* bq = (const float*)d_in[4];
  const float* wk = (const float*)d_in[5];
  const float* bk = (const float*)d_in[6];
  const float* wv = (const float*)d_in[7];
  const float* bv = (const float*)d_in[8];
  const float* wo = (const float*)d_in[9];
  const float* bo = (const float*)d_in[10];
  float* out = (float*)d_out;

  char* ws = (char*)d_ws;
  const size_t MB = 1024 * 1024;
  US* qb  = (US*)(ws + 0 * MB);
  US* kb  = (US*)(ws + 8 * MB);
  US* vb  = (US*)(ws + 16 * MB);
  US* wqT = (US*)(ws + 24 * MB);  // wqT/wkT/wvT contiguous -> fused [3072][1024]
  US* wkT = (US*)(ws + 26 * MB);
  US* wvT = (US*)(ws + 28 * MB);
  US* woT = (US*)(ws + 30 * MB);
  US* qh  = (US*)(ws + 32 * MB);  // [B,H,S,D] (pre-scaled by log2e)
  US* kh  = (US*)(ws + 40 * MB);  // [B,H,S,D]
  US* vt  = (US*)(ws + 48 * MB);  // [B,H,D,S]
  US* ao  = (US*)(ws + 56 * MB);  // [B*S, 1024]

  prep_kernel<<<7168, 256, 0, stream>>>(q, k, v, wq, wk, wv, wo,
                                        qb, kb, vb, wqT, wkT, wvT, woT);
  gemm_qkv_kernel<<<dim3(32, 24), 256, 0, stream>>>(qb, kb, vb, wqT,
                                                    bq, bk, bv, qh, kh, vt);
  attn_kernel<<<dim3(32, 16), 512, 0, stream>>>(qh, kh, vt, ao);
  gemm_out_kernel<<<dim3(32, 16), 256, 0, stream>>>(ao, woT, bo, out);
}